// Round 1
// baseline (151.184 us; speedup 1.0000x reference)
//
#include <hip/hip_runtime.h>
#include <math.h>

// ---------------------------------------------------------------------------
// A3C_LSTM_GA forward, batch=1.  Latency-bound: critical path is the 64-step
// GRU scan (hidden 256, wh 768x256).  Strategy:
//   k_init : sentinel-fill h_buf slots 1..64, zero tail flags
//   k_main : blocks 0-7  GRU scan, wh register-resident (96 KB/WG),
//                        cross-WG sync via data-as-flag (NaN sentinel)
//            block  8    image MLP 400->128->128->128
//            blocks 9-12 gates_h = hx @ lstm_wh.T + lstm_bh   (hidden under scan)
//   k_tail : block  0    attn -> fuse -> lin -> (wait) heads
//            blocks 1-4  lstm_wi gates (prefetch L2 while spinning), c/h update
// ---------------------------------------------------------------------------

#define SENT_U 0xFFC0DEADu  // NaN bit pattern; real h is tanh/sigmoid-bounded

// ws layout (float offsets)
#define WS_HBUF   0        // 65*256 floats; slot s+1 holds h after step s
#define WS_FLAGS  16640    // 2 ints: F1 (fused ready), F2 (h_new count)
#define WS_IMG    16704    // 128
#define WS_GATESH 16832    // 1024
#define WS_FUSED  17856    // 256
#define WS_HNEW   18112    // 256   (total 18368 floats = 73.5 KB)

__device__ __forceinline__ float dot4(const float4 a, const float4 b){
  return a.x*b.x + a.y*b.y + a.z*b.z + a.w*b.w;
}
__device__ __forceinline__ float sigm(float x){ return 1.f/(1.f+expf(-x)); }
__device__ __forceinline__ float aload(const float* p){
  return __hip_atomic_load(p, __ATOMIC_RELAXED, __HIP_MEMORY_SCOPE_AGENT);
}
__device__ __forceinline__ void astore(float* p, float v){
  __hip_atomic_store(p, v, __ATOMIC_RELAXED, __HIP_MEMORY_SCOPE_AGENT);
}

__global__ __launch_bounds__(256) void a3c_init(float* __restrict__ ws){
  const int i = blockIdx.x*256 + threadIdx.x;           // grid 64*256 = 16384
  ((unsigned*)(ws + WS_HBUF + 256))[i] = SENT_U;        // slots 1..64
  if (i < 2) ((int*)(ws + WS_FLAGS))[i] = 0;
}

__global__ __launch_bounds__(256) void a3c_main(
    const int*   __restrict__ inst, const float* __restrict__ emb,
    const float* __restrict__ gwi,  const float* __restrict__ gwh,
    const float* __restrict__ gbi,  const float* __restrict__ gbh,
    const float* __restrict__ x,
    const float* __restrict__ i1w,  const float* __restrict__ i1b,
    const float* __restrict__ i2w,  const float* __restrict__ i2b,
    const float* __restrict__ i3w,  const float* __restrict__ i3b,
    const float* __restrict__ hx,   const float* __restrict__ lwh,
    const float* __restrict__ lbh,  float* __restrict__ ws)
{
  const int b = blockIdx.x;
  const int t = threadIdx.x;

  if (b < 8) {
    // ----------------- GRU scan: this WG owns hidden units [b*32, b*32+32)
    __shared__ __align__(16) float h_lds[256];
    __shared__ float gi_lds[64*96];                  // [step][local row]
    __shared__ __align__(16) float emb_lds[64*32];
    const int u   = t >> 3;       // local unit 0..31
    const int sub = t & 7;        // column slice 0..7 (32 cols each)
    const int U   = b*32 + u;     // global unit

    // wh fragments in registers: 3 gates x 32 cols = 96 VGPRs/thread
    float4 wv0[8], wv1[8], wv2[8];
    {
      const float4* p0 = (const float4*)(gwh + (0*256 + U)*256 + sub*32);
      const float4* p1 = (const float4*)(gwh + (1*256 + U)*256 + sub*32);
      const float4* p2 = (const float4*)(gwh + (2*256 + U)*256 + sub*32);
      #pragma unroll
      for (int k=0;k<8;++k){ wv0[k]=p0[k]; wv1[k]=p1[k]; wv2[k]=p2[k]; }
    }
    const float bh0 = gbh[U], bh1 = gbh[256+U], bh2 = gbh[512+U];

    for (int i=t; i<64*32; i+=256)
      emb_lds[i] = emb[inst[i>>5]*32 + (i&31)];
    h_lds[t] = 0.f;
    __syncthreads();

    // gi[s][row] = gru_wi[row] . emb_s + gbi[row], rows for our 96 gate-rows
    if (t < 192){
      const int lr = t>>1, half = t&1;
      const int g = lr>>5, ul = lr&31;
      const int grow = (g<<8) + b*32 + ul;
      float4 wi[8];
      const float4* wip = (const float4*)(gwi + grow*32);
      #pragma unroll
      for (int k=0;k<8;++k) wi[k]=wip[k];
      const float bi = gbi[grow];
      for (int s=half*32; s<half*32+32; ++s){
        const float4* e4 = (const float4*)(emb_lds + s*32);
        float acc = bi;
        #pragma unroll
        for (int k=0;k<8;++k) acc += dot4(wi[k], e4[k]);
        gi_lds[s*96 + lr] = acc;
      }
    }
    __syncthreads();

    float* hb = ws + WS_HBUF;
    for (int s=0; s<64; ++s){
      const float4* h4 = (const float4*)(h_lds + sub*32);
      float p0=0.f, p1=0.f, p2=0.f;
      #pragma unroll
      for (int k=0;k<8;++k){
        const float4 h = h4[k];
        p0 += dot4(wv0[k], h);
        p1 += dot4(wv1[k], h);
        p2 += dot4(wv2[k], h);
      }
      #pragma unroll
      for (int off=4; off; off>>=1){
        p0 += __shfl_down(p0, off, 8);
        p1 += __shfl_down(p1, off, 8);
        p2 += __shfl_down(p2, off, 8);
      }
      const float h_old = h_lds[U];
      if (sub == 0){
        const float* gis = gi_lds + s*96;
        const float r = sigm(gis[u]      + p0 + bh0);
        const float z = sigm(gis[32 + u] + p1 + bh1);
        const float n = tanhf(gis[64 + u] + r*(p2 + bh2));
        astore(&hb[(s+1)*256 + U], (1.f - z)*n + z*h_old);
      }
      __syncthreads();  // order stores before polls; all compute reads of h_lds done
      float v;
      do { v = aload(&hb[(s+1)*256 + t]); } while (__float_as_uint(v) == SENT_U);
      h_lds[t] = v;
      __syncthreads();
    }
    // h_buf slot 64 = h_enc, consumed by k_tail

  } else if (b == 8) {
    // ----------------- image MLP 400 -> 128 -> 128 -> 128
    __shared__ __align__(16) float x_lds[400];
    __shared__ __align__(16) float h1[128];
    __shared__ __align__(16) float h2[128];
    x_lds[t] = x[t];
    if (t < 144) x_lds[256+t] = x[256+t];
    __syncthreads();
    {
      const int o = t>>1, half = t&1;
      const float4* wr = (const float4*)(i1w + o*400 + half*200);
      const float4* xr = (const float4*)(x_lds + half*200);
      float acc = 0.f;
      #pragma unroll 5
      for (int k=0;k<50;++k) acc += dot4(wr[k], xr[k]);
      acc += __shfl_down(acc, 1, 2);
      if (half == 0) h1[o] = fmaxf(acc + i1b[o], 0.f);
    }
    __syncthreads();
    if (t < 128){
      const float4* wr = (const float4*)(i2w + t*128);
      const float4* h4 = (const float4*)h1;
      float acc = i2b[t];
      #pragma unroll 8
      for (int k=0;k<32;++k) acc += dot4(wr[k], h4[k]);
      h2[t] = fmaxf(acc, 0.f);
    }
    __syncthreads();
    if (t < 128){
      const float4* wr = (const float4*)(i3w + t*128);
      const float4* h4 = (const float4*)h2;
      float acc = i3b[t];
      #pragma unroll 8
      for (int k=0;k<32;++k) acc += dot4(wr[k], h4[k]);
      ws[WS_IMG + t] = fmaxf(acc, 0.f);     // consumed next kernel: plain store ok
    }

  } else {
    // ----------------- gates_h = hx @ lstm_wh.T + lstm_bh  (blocks 9..12)
    __shared__ __align__(16) float hx_lds[256];
    hx_lds[t] = hx[t];
    __syncthreads();
    const int R = (b-9)*256 + t;
    const float4* wr = (const float4*)(lwh + R*256);
    const float4* h4 = (const float4*)hx_lds;
    float acc = lbh[R];
    #pragma unroll 8
    for (int k=0;k<64;++k) acc += dot4(wr[k], h4[k]);
    ws[WS_GATESH + R] = acc;
  }
}

__global__ __launch_bounds__(256) void a3c_tail(
    const float* __restrict__ aw,  const float* __restrict__ ab,
    const float* __restrict__ lw,  const float* __restrict__ lb,
    const float* __restrict__ lwi, const float* __restrict__ lbi,
    const float* __restrict__ cx,  const int*   __restrict__ tx,
    const float* __restrict__ temb,
    const float* __restrict__ cw,  const float* __restrict__ cb,
    const float* __restrict__ acw, const float* __restrict__ acb,
    float* __restrict__ ws, float* __restrict__ out)
{
  const int b = blockIdx.x;
  const int t = threadIdx.x;
  int* F = (int*)(ws + WS_FLAGS);

  if (b == 0) {
    // attn(sigmoid) * image_rep -> lin(relu) -> publish fused; then heads
    __shared__ __align__(16) float henc[256];
    __shared__ __align__(16) float f0[128];
    __shared__ __align__(16) float feat[288];
    __shared__ float red[4];
    henc[t] = ws[WS_HBUF + 64*256 + t];
    __syncthreads();
    if (t < 128){
      const float4* wr = (const float4*)(aw + t*256);
      const float4* h4 = (const float4*)henc;
      float acc = ab[t];
      #pragma unroll 8
      for (int k=0;k<64;++k) acc += dot4(wr[k], h4[k]);
      f0[t] = ws[WS_IMG + t] * sigm(acc);
    }
    __syncthreads();
    {
      const float4* wr = (const float4*)(lw + t*128);
      const float4* h4 = (const float4*)f0;
      float acc = lb[t];
      #pragma unroll 8
      for (int k=0;k<32;++k) acc += dot4(wr[k], h4[k]);
      astore(ws + WS_FUSED + t, fmaxf(acc, 0.f));
    }
    __syncthreads();
    if (t == 0){
      __threadfence();
      __hip_atomic_store(&F[0], 1, __ATOMIC_RELEASE, __HIP_MEMORY_SCOPE_AGENT);
      while (__hip_atomic_load(&F[1], __ATOMIC_ACQUIRE, __HIP_MEMORY_SCOPE_AGENT) < 4){}
    }
    __syncthreads();
    feat[t] = aload(ws + WS_HNEW + t);
    if (t < 32) feat[256+t] = temb[tx[0]*32 + t];
    __syncthreads();
    for (int o=0; o<5; ++o){
      const float* wrow = (o==0) ? cw : (acw + (o-1)*288);
      float pr = feat[t]*wrow[t];
      if (t < 32) pr += feat[256+t]*wrow[256+t];
      #pragma unroll
      for (int off=32; off; off>>=1) pr += __shfl_down(pr, off, 64);
      if ((t&63)==0) red[t>>6] = pr;
      __syncthreads();
      if (t == 0) out[o] = red[0]+red[1]+red[2]+red[3] + (o==0 ? cb[0] : acb[o-1]);
      __syncthreads();
    }

  } else {
    // blocks 1..4: 256 LSTM gate rows each; prefetch weights while waiting
    const int p = b - 1;
    __shared__ __align__(16) float fused_lds[256];
    __shared__ float gv[256];
    const int g = t >> 6, ul = t & 63;
    const int R = (g<<8) + p*64 + ul;
    const float4* wr = (const float4*)(lwi + R*256);
    float pf = 0.f;
    for (int k=0;k<64;++k){ float4 w = wr[k]; pf += w.x+w.y+w.z+w.w; }
    asm volatile("" :: "v"(pf));                       // keep prefetch live
    const float gh = ws[WS_GATESH + R] + lbi[R];
    if (t == 0){
      while (__hip_atomic_load(&F[0], __ATOMIC_ACQUIRE, __HIP_MEMORY_SCOPE_AGENT) == 0){}
    }
    __syncthreads();
    fused_lds[t] = aload(ws + WS_FUSED + t);
    __syncthreads();
    float acc = gh;
    const float4* f4 = (const float4*)fused_lds;
    #pragma unroll 8
    for (int k=0;k<64;++k) acc += dot4(wr[k], f4[k]);
    gv[t] = acc;                                       // [gate*64 + unit]
    __syncthreads();
    if (t < 64){
      const int u2 = p*64 + t;
      const float iv = gv[t], fv = gv[64+t], gg = gv[128+t], ov = gv[192+t];
      const float c = sigm(fv)*cx[u2] + sigm(iv)*tanhf(gg);
      const float h = sigm(ov)*tanhf(c);
      out[5   + u2] = h;
      out[261 + u2] = c;
      astore(ws + WS_HNEW + u2, h);
    }
    __syncthreads();
    if (t == 0){
      __threadfence();
      __hip_atomic_fetch_add(&F[1], 1, __ATOMIC_RELEASE, __HIP_MEMORY_SCOPE_AGENT);
    }
  }
}

extern "C" void kernel_launch(void* const* d_in, const int* in_sizes, int n_in,
                              void* d_out, int out_size, void* d_ws, size_t ws_size,
                              hipStream_t stream) {
  (void)in_sizes; (void)n_in; (void)out_size; (void)ws_size;
  const float* x    = (const float*)d_in[0];
  const int*   inst = (const int*)  d_in[1];
  const int*   tx   = (const int*)  d_in[2];
  const float* hx   = (const float*)d_in[3];
  const float* cx   = (const float*)d_in[4];
  const float* i1w  = (const float*)d_in[5];
  const float* i1b  = (const float*)d_in[6];
  const float* i2w  = (const float*)d_in[7];
  const float* i2b  = (const float*)d_in[8];
  const float* i3w  = (const float*)d_in[9];
  const float* i3b  = (const float*)d_in[10];
  const float* emb  = (const float*)d_in[11];
  const float* gwi  = (const float*)d_in[12];
  const float* gwh  = (const float*)d_in[13];
  const float* gbi  = (const float*)d_in[14];
  const float* gbh  = (const float*)d_in[15];
  const float* aw   = (const float*)d_in[16];
  const float* ab   = (const float*)d_in[17];
  const float* temb = (const float*)d_in[18];
  const float* lw   = (const float*)d_in[19];
  const float* lb   = (const float*)d_in[20];
  const float* lwi  = (const float*)d_in[21];
  const float* lwh  = (const float*)d_in[22];
  const float* lbi  = (const float*)d_in[23];
  const float* lbh  = (const float*)d_in[24];
  const float* cw   = (const float*)d_in[25];
  const float* cb   = (const float*)d_in[26];
  const float* acw  = (const float*)d_in[27];
  const float* acb  = (const float*)d_in[28];
  float* ws  = (float*)d_ws;
  float* out = (float*)d_out;

  a3c_init<<<64, 256, 0, stream>>>(ws);
  a3c_main<<<13, 256, 0, stream>>>(inst, emb, gwi, gwh, gbi, gbh,
                                   x, i1w, i1b, i2w, i2b, i3w, i3b,
                                   hx, lwh, lbh, ws);
  a3c_tail<<<5, 256, 0, stream>>>(aw, ab, lw, lb, lwi, lbi, cx, tx, temb,
                                  cw, cb, acw, acb, ws, out);
}